// Round 9
// baseline (28167.773 us; speedup 1.0000x reference)
//
#include <hip/hip_runtime.h>
#include <hip/hip_bf16.h>
#include <cstddef>
#include <cstdint>

// B=32, T=2048, D=64, H=256, O=32, 4H=1024
#define BB 32
#define TT 2048
#define DD 64
#define HH 256
#define OO 32
#define NBLK 8   // blocks per layer

#define OUT_ELEMS (BB*TT*OO)
#define HN_OFF OUT_ELEMS
#define CN_OFF (HN_OFF + 2*BB*HH)

// ---------------- workspace byte offsets ----------------
// Tagged h buffers: dword = (bf16 << 16) | tag, tag(slot) = slot+1.
// h0t/h1t: [2049 slots][32 b][256 h] dwords = 67,141,632 B each.
#define O_H0T   ((size_t)0)
#define O_H1T   ((size_t)67141632)
#define TAGBYTES ((size_t)134283264)            // both tag buffers (memset 0)
#define O_WP0   ((size_t)134283264)             // Wperm0 bf16 [1024][320]
#define O_WP1   ((size_t)134938624)             // Wperm1 bf16 [1024][512]
#define O_B0    ((size_t)135987200)             // bias0 f32 [1024]
#define O_B1    ((size_t)135991296)             // bias1 f32 [1024]
#define O_WD0T  ((size_t)135995392)             // [256][256] f32 transposed
#define O_WD1T  ((size_t)136257536)
#define O_WOUT  ((size_t)136519680)             // [256][32] f32
// end: 136,552,448 B  (< 138.2 MB proven available in round 1)

typedef short short8 __attribute__((ext_vector_type(8)));
typedef float f32x4 __attribute__((ext_vector_type(4)));
typedef unsigned int uint4v __attribute__((ext_vector_type(4)));
typedef unsigned long long ull;

__device__ __forceinline__ float sigm_(float x){ return 1.0f/(1.0f+__expf(-x)); }
__device__ __forceinline__ float tanhf_(float x){
    float xc = fminf(fmaxf(x, -15.0f), 15.0f);
    float e = __expf(2.0f*xc);
    return (e-1.0f)/(e+1.0f);
}
__device__ __forceinline__ unsigned short f2bf(float f){
    __hip_bfloat16 h = __float2bfloat16(f);
    return *reinterpret_cast<unsigned short*>(&h);
}
__device__ __forceinline__ short8 ld8(const unsigned short* p){
    return *reinterpret_cast<const short8*>(p);
}

// Pack a k-tile's 8 tagged dwords (h ascending) into a bf16x8 B-fragment.
__device__ __forceinline__ short8 packtile(uint4v a, uint4v b){
    uint4v u;
    u.x = (a.y & 0xffff0000u) | (a.x >> 16);
    u.y = (a.w & 0xffff0000u) | (a.z >> 16);
    u.z = (b.y & 0xffff0000u) | (b.x >> 16);
    u.w = (b.w & 0xffff0000u) | (b.z >> 16);
    return __builtin_bit_cast(short8, u);
}
// 8 f32 -> bf16x8 (RN, same numerics as prior prep conversion).
__device__ __forceinline__ short8 cvt8(float4 a, float4 b){
    uint4v u;
    u.x = ((unsigned)f2bf(a.y)<<16) | f2bf(a.x);
    u.y = ((unsigned)f2bf(a.w)<<16) | f2bf(a.z);
    u.z = ((unsigned)f2bf(b.y)<<16) | f2bf(b.x);
    u.w = ((unsigned)f2bf(b.w)<<16) | f2bf(b.z);
    return __builtin_bit_cast(short8, u);
}

// Validate 8 k-tiles (16B+16B each).  Tag check per 8B-atomic-store unit
// (dwords 0,2 of each 16B half -> x,z).  Stale tiles are batch-reloaded with
// agent-scope 8B atomic loads (L1-bypass, LLC-fresh — proven rounds 2-5).
// Capped: a visibility bug fails validation loudly instead of hanging.
__device__ __forceinline__ void validate8(const unsigned int* base,
                                          uint4v* va, uint4v* vb, unsigned tg)
{
    int it = 0;
    while (true) {
        unsigned bad = 0;
#pragma unroll
        for (int kk = 0; kk < 8; ++kk) {
            unsigned m = ((va[kk].x ^ tg) | (va[kk].z ^ tg) |
                          (vb[kk].x ^ tg) | (vb[kk].z ^ tg)) & 0xffffu;
            if (m) bad |= 1u << kk;
        }
        if (bad == 0) return;
#pragma unroll
        for (int kk = 0; kk < 8; ++kk) {
            if (bad & (1u << kk)) {
                const ull* p = (const ull*)(base + kk*32);
                ull u0 = __hip_atomic_load(p+0, __ATOMIC_RELAXED, __HIP_MEMORY_SCOPE_AGENT);
                ull u1 = __hip_atomic_load(p+1, __ATOMIC_RELAXED, __HIP_MEMORY_SCOPE_AGENT);
                ull u2 = __hip_atomic_load(p+2, __ATOMIC_RELAXED, __HIP_MEMORY_SCOPE_AGENT);
                ull u3 = __hip_atomic_load(p+3, __ATOMIC_RELAXED, __HIP_MEMORY_SCOPE_AGENT);
                va[kk].x = (unsigned)u0; va[kk].y = (unsigned)(u0>>32);
                va[kk].z = (unsigned)u1; va[kk].w = (unsigned)(u1>>32);
                vb[kk].x = (unsigned)u2; vb[kk].y = (unsigned)(u2>>32);
                vb[kk].z = (unsigned)u3; vb[kk].w = (unsigned)(u3>>32);
            }
        }
        if (++it > 4096) return;   // bug -> wrong output, not a hang
    }
}

// ---------------------------------------------------------------------------
// Prep: weight-row permutation (identical math to rounds 4-5), bias sums,
// slot-0 tagged h inits, head-weight transposes.  total = 1,009,664 = 3944*256
// ---------------------------------------------------------------------------
__global__ void prep_kernel(const float* __restrict__ h0,
    const float* __restrict__ Wih0, const float* __restrict__ Whh0,
    const float* __restrict__ bih0, const float* __restrict__ bhh0,
    const float* __restrict__ Wih1, const float* __restrict__ Whh1,
    const float* __restrict__ bih1, const float* __restrict__ bhh1,
    const float* __restrict__ Wd0, const float* __restrict__ Wd1,
    const float* __restrict__ Wout, char* __restrict__ ws)
{
    int i = blockIdx.x*256 + threadIdx.x;
    if (i < 327680) {   // Wperm0 [1024][320]
        int R = i / 320, k = i - R*320;
        int lrow = R & 15, s = (R>>4)&1, hr = (R>>5)&3, jj = R>>7;
        int gate = 2*s + (lrow>>3);
        int h = 32*jj + 8*hr + (lrow&7);
        int src = 256*gate + h;
        float v = (k < 64) ? Wih0[src*64 + k] : Whh0[src*256 + (k-64)];
        ((unsigned short*)(ws+O_WP0))[i] = f2bf(v);
        return;
    }
    i -= 327680;
    if (i < 524288) {   // Wperm1 [1024][512]
        int R = i >> 9, k = i & 511;
        int lrow = R & 15, s = (R>>4)&1, hr = (R>>5)&3, jj = R>>7;
        int gate = 2*s + (lrow>>3);
        int h = 32*jj + 8*hr + (lrow&7);
        int src = 256*gate + h;
        float v = (k < 256) ? Wih1[src*256 + k] : Whh1[src*256 + (k-256)];
        ((unsigned short*)(ws+O_WP1))[i] = f2bf(v);
        return;
    }
    i -= 524288;
    if (i < 1024) { ((float*)(ws+O_B0))[i] = bih0[i] + bhh0[i]; return; }
    i -= 1024;
    if (i < 1024) { ((float*)(ws+O_B1))[i] = bih1[i] + bhh1[i]; return; }
    i -= 1024;
    if (i < 8192) {     // h0t slot 0: tag 1
        ((unsigned int*)(ws+O_H0T))[i] = ((unsigned)f2bf(h0[i])<<16) | 1u;
        return;
    }
    i -= 8192;
    if (i < 8192) {     // h1t slot 0: tag 1
        ((unsigned int*)(ws+O_H1T))[i] = ((unsigned)f2bf(h0[8192+i])<<16) | 1u;
        return;
    }
    i -= 8192;
    if (i < 65536) { int o = i & 255, h = i >> 8; ((float*)(ws+O_WD0T))[i] = Wd0[o*256 + h]; return; }
    i -= 65536;
    if (i < 65536) { int o = i & 255, h = i >> 8; ((float*)(ws+O_WD1T))[i] = Wd1[o*256 + h]; return; }
    i -= 65536;
    if (i < 8192) { int o = i & 31, h = i >> 5; ((float*)(ws+O_WOUT))[i] = Wout[o*256 + h]; return; }
}

// ---------------------------------------------------------------------------
// Persistent LSTM, tag-synchronized, barrier-free.  8 blocks/layer x 512
// threads (8 waves).  Wave (hr,bh) of block j owns all 4 gates for h-range
// [32j+8hr,+8) x batches [16bh,+16).  A-frags pinned in VGPRs.  Per step:
// plain wide loads of tagged inputs -> tag validate (agent-retry) -> MFMA ->
// shfl_xor register gate combine -> tagged agent stores.  NO barriers, NO
// flags, NO fences in the loop.
// mfma_f32_16x16x32_bf16: A lane l -> A[row=l&15][k=(l>>4)*8+j];
//                         B lane l -> B[k][col=l&15];
//                         D lane l -> D[row=(l>>4)*4+r][col=l&15].
// ---------------------------------------------------------------------------
template<int L>
__device__ void lstm_body(int j, char* ws, const float* __restrict__ xin,
                          const float* __restrict__ c0_in, float* __restrict__ out)
{
    constexpr int KK  = L ? 512 : 320;
    constexpr int NKT = KK / 32;

    const int tid  = threadIdx.x;
    const int wv   = tid >> 6;
    const int lane = tid & 63;
    const int bh   = wv >> 2;
    const int hr   = wv & 3;
    const int lrow = lane & 15;
    const int q    = lane >> 4;
    const int koff = q * 8;
    const int qe   = q & 1;
    const int fb   = bh*16 + lrow;             // batch (B-frag col & combine col)
    const int hbase= 32*j + 8*hr + 4*qe;       // global h base (combine rows +r)
    const bool lo  = (lane < 32);

    const unsigned short* Wp = (const unsigned short*)(ws + (L ? O_WP1 : O_WP0));
    const float* bias = (const float*)(ws + (L ? O_B1 : O_B0));

    const int wavebase = (j*4 + hr) * 32;
    short8 a0[NKT], a1[NKT];
#pragma unroll
    for (int kk = 0; kk < NKT; ++kk) {
        a0[kk] = ld8(Wp + (size_t)(wavebase +      lrow)*KK + kk*32 + koff);
        a1[kk] = ld8(Wp + (size_t)(wavebase + 16 + lrow)*KK + kk*32 + koff);
    }

    float bi[4], bf_[4], bg[4], bo[4], c[4], hv[4];
#pragma unroll
    for (int r = 0; r < 4; ++r) {
        int hg = hbase + r;
        bi[r] = bias[hg];       bf_[r] = bias[256+hg];
        bg[r] = bias[512+hg];   bo[r]  = bias[768+hg];
        c[r]  = c0_in[(size_t)L*8192 + fb*256 + hg];
        hv[r] = 0.f;
    }

    const unsigned int* h0t = (const unsigned int*)(ws + O_H0T);
    const unsigned int* h1t = (const unsigned int*)(ws + O_H1T);
    unsigned int* dst = (unsigned int*)(ws + (L ? O_H1T : O_H0T));
    const size_t laneoff = (size_t)fb*256 + koff;

    for (int t = 0; t < TT; ++t) {
        f32x4 A0 = {0.f,0.f,0.f,0.f}, A1 = {0.f,0.f,0.f,0.f};

        if (L == 0) {
            // x: static f32 input, convert on the fly (k-tiles 0-1)
            const float4* xp4 = (const float4*)(xin + ((size_t)fb*TT + t)*64 + koff);
            float4 x0 = xp4[0], x1 = xp4[1];
            float4 x2 = xp4[8], x3 = xp4[9];

            // h0[t] (tag t+1): issue all loads, validate, MFMA
            const unsigned int* hp = h0t + (size_t)t*8192 + laneoff;
            uint4v va[8], vb[8];
#pragma unroll
            for (int kk = 0; kk < 8; ++kk) {
                va[kk] = *(const uint4v*)(hp + kk*32);
                vb[kk] = *(const uint4v*)(hp + kk*32 + 4);
            }
            short8 bx0 = cvt8(x0, x1), bx1 = cvt8(x2, x3);
            A0 = __builtin_amdgcn_mfma_f32_16x16x32_bf16(a0[0], bx0, A0, 0,0,0);
            A1 = __builtin_amdgcn_mfma_f32_16x16x32_bf16(a1[0], bx0, A1, 0,0,0);
            A0 = __builtin_amdgcn_mfma_f32_16x16x32_bf16(a0[1], bx1, A0, 0,0,0);
            A1 = __builtin_amdgcn_mfma_f32_16x16x32_bf16(a1[1], bx1, A1, 0,0,0);

            validate8(hp, va, vb, (unsigned)(t+1));
#pragma unroll
            for (int kk = 0; kk < 8; ++kk) {
                short8 bfr = packtile(va[kk], vb[kk]);
                A0 = __builtin_amdgcn_mfma_f32_16x16x32_bf16(a0[2+kk], bfr, A0, 0,0,0);
                A1 = __builtin_amdgcn_mfma_f32_16x16x32_bf16(a1[2+kk], bfr, A1, 0,0,0);
            }
        } else {
            // part A: y0[t] = h0t slot t+1 (tag t+2) — L0 runs ahead, rarely waits
            {
                const unsigned int* ap = h0t + (size_t)(t+1)*8192 + laneoff;
                uint4v va[8], vb[8];
#pragma unroll
                for (int kk = 0; kk < 8; ++kk) {
                    va[kk] = *(const uint4v*)(ap + kk*32);
                    vb[kk] = *(const uint4v*)(ap + kk*32 + 4);
                }
                validate8(ap, va, vb, (unsigned)(t+2));
#pragma unroll
                for (int kk = 0; kk < 8; ++kk) {
                    short8 bfr = packtile(va[kk], vb[kk]);
                    A0 = __builtin_amdgcn_mfma_f32_16x16x32_bf16(a0[kk], bfr, A0, 0,0,0);
                    A1 = __builtin_amdgcn_mfma_f32_16x16x32_bf16(a1[kk], bfr, A1, 0,0,0);
                }
            }
            // part B: h1 self-recurrence, slot t (tag t+1) — the critical chain
            {
                const unsigned int* bp = h1t + (size_t)t*8192 + laneoff;
                uint4v va[8], vb[8];
#pragma unroll
                for (int kk = 0; kk < 8; ++kk) {
                    va[kk] = *(const uint4v*)(bp + kk*32);
                    vb[kk] = *(const uint4v*)(bp + kk*32 + 4);
                }
                validate8(bp, va, vb, (unsigned)(t+1));
#pragma unroll
                for (int kk = 0; kk < 8; ++kk) {
                    short8 bfr = packtile(va[kk], vb[kk]);
                    A0 = __builtin_amdgcn_mfma_f32_16x16x32_bf16(a0[8+kk], bfr, A0, 0,0,0);
                    A1 = __builtin_amdgcn_mfma_f32_16x16x32_bf16(a1[8+kk], bfr, A1, 0,0,0);
                }
            }
        }

        // --- register combine: swap lane<->lane+32 pairs (i,f) and (g,o) ---
#pragma unroll
        for (int r = 0; r < 4; ++r) {
            float x0 = A0[r], y0 = __shfl_xor(x0, 32, 64);
            float x1 = A1[r], y1 = __shfl_xor(x1, 32, 64);
            float gi = (lo ? x0 : y0) + bi[r];
            float gf = (lo ? y0 : x0) + bf_[r];
            float gg = (lo ? x1 : y1) + bg[r];
            float go = (lo ? y1 : x1) + bo[r];
            float iv = sigm_(gi), fv = sigm_(gf), gv = tanhf_(gg), ov = sigm_(go);
            c[r]  = fv*c[r] + iv*gv;
            hv[r] = ov * tanhf_(c[r]);
        }

        // --- tagged stores: slot t+1, tag t+2 (each 8B store atomic) ---
        if (lo) {
            const unsigned tg = (unsigned)(t + 2);
            unsigned d0 = ((unsigned)f2bf(hv[0])<<16) | tg;
            unsigned d1 = ((unsigned)f2bf(hv[1])<<16) | tg;
            unsigned d2 = ((unsigned)f2bf(hv[2])<<16) | tg;
            unsigned d3 = ((unsigned)f2bf(hv[3])<<16) | tg;
            unsigned int* dp = dst + (size_t)(t+1)*8192 + (size_t)fb*256 + hbase;
            __hip_atomic_store((ull*)dp,     (ull)d0 | ((ull)d1<<32),
                               __ATOMIC_RELAXED, __HIP_MEMORY_SCOPE_AGENT);
            __hip_atomic_store((ull*)dp + 1, (ull)d2 | ((ull)d3<<32),
                               __ATOMIC_RELAXED, __HIP_MEMORY_SCOPE_AGENT);
        }
    }

    if (lo) {
#pragma unroll
        for (int r = 0; r < 4; ++r) {
            out[HN_OFF + (size_t)L*8192 + fb*256 + hbase + r] = hv[r];
            out[CN_OFF + (size_t)L*8192 + fb*256 + hbase + r] = c[r];
        }
    }
}

__global__ __launch_bounds__(512, 2) void lstm_fused(char* ws,
                                                     const float* __restrict__ xin,
                                                     const float* __restrict__ c0_in,
                                                     float* __restrict__ out)
{
    if (blockIdx.x < NBLK) lstm_body<0>(blockIdx.x, ws, xin, c0_in, out);
    else                   lstm_body<1>(blockIdx.x - NBLK, ws, xin, c0_in, out);
}

// ---------------------------------------------------------------------------
// Fused dense head: reads y1 = h1t slot t+1 (strip tag: dword & 0xffff0000
// reinterpreted as f32 IS the bf16 value).
// ---------------------------------------------------------------------------
__global__ __launch_bounds__(256) void head_kernel(const char* __restrict__ ws,
    const float* __restrict__ bd0, const float* __restrict__ bd1,
    const float* __restrict__ bout, float* __restrict__ out)
{
    const unsigned int* h1t = (const unsigned int*)(ws + O_H1T);
    const float* Wd0T  = (const float*)(ws + O_WD0T);
    const float* Wd1T  = (const float*)(ws + O_WD1T);
    const float* WoutT = (const float*)(ws + O_WOUT);

    __shared__ float buf0[16][256];
    __shared__ float buf1[16][256];
    const int row0 = blockIdx.x * 16;
    const int tid = threadIdx.x;

#pragma unroll
    for (int i = 0; i < 16; ++i) {
        int r = row0 + i;
        int b = r >> 11, t = r & 2047;
        unsigned int d = h1t[(size_t)(t+1)*8192 + b*256 + tid];
        buf0[i][tid] = __uint_as_float(d & 0xffff0000u);
    }
    __syncthreads();

    {   // stage 1: Linear+ReLU
        float acc[16];
        float bv = bd0[tid];
#pragma unroll
        for (int r = 0; r < 16; ++r) acc[r] = bv;
        for (int h = 0; h < 256; ++h) {
            float w = Wd0T[h*256 + tid];
#pragma unroll
            for (int r = 0; r < 16; ++r) acc[r] += w * buf0[r][h];
        }
        __syncthreads();
#pragma unroll
        for (int r = 0; r < 16; ++r) buf1[r][tid] = fmaxf(acc[r], 0.0f);
    }
    __syncthreads();

    {   // stage 2: Linear+ReLU
        float acc[16];
        float bv = bd1[tid];
#pragma unroll
        for (int r = 0; r < 16; ++r) acc[r] = bv;
        for (int h = 0; h < 256; ++h) {
            float w = Wd1T[h*256 + tid];
#pragma unroll
            for (int r = 0; r < 16; ++r) acc[r] += w * buf1[r][h];
        }
        __syncthreads();
#pragma unroll
        for (int r = 0; r < 16; ++r) buf0[r][tid] = fmaxf(acc[r], 0.0f);
    }
    __syncthreads();

    {   // stage 3: output Linear
        const int o = tid & 31;
        const int rr = tid >> 5;
        float a0 = bout[o], a1 = bout[o];
        for (int h = 0; h < 256; ++h) {
            float w = WoutT[h*32 + o];
            a0 += w * buf0[rr*2 + 0][h];
            a1 += w * buf0[rr*2 + 1][h];
        }
        out[(size_t)(row0 + rr*2 + 0)*32 + o] = a0;
        out[(size_t)(row0 + rr*2 + 1)*32 + o] = a1;
    }
}

// ---------------------------------------------------------------------------
extern "C" void kernel_launch(void* const* d_in, const int* in_sizes, int n_in,
                              void* d_out, int out_size, void* d_ws, size_t ws_size,
                              hipStream_t stream) {
    const float* x    = (const float*)d_in[0];
    const float* h0   = (const float*)d_in[1];
    const float* c0   = (const float*)d_in[2];
    const float* Wih0 = (const float*)d_in[3];
    const float* Whh0 = (const float*)d_in[4];
    const float* bih0 = (const float*)d_in[5];
    const float* bhh0 = (const float*)d_in[6];
    const float* Wih1 = (const float*)d_in[7];
    const float* Whh1 = (const float*)d_in[8];
    const float* bih1 = (const float*)d_in[9];
    const float* bhh1 = (const float*)d_in[10];
    const float* Wd0  = (const float*)d_in[11];
    const float* bd0  = (const float*)d_in[12];
    const float* Wd1  = (const float*)d_in[13];
    const float* bd1  = (const float*)d_in[14];
    const float* Wout = (const float*)d_in[15];
    const float* bout = (const float*)d_in[16];

    char* ws = (char*)d_ws;
    float* out = (float*)d_out;

    // Zero both tag buffers each launch (replay-safe: stale tags killed).
    hipMemsetAsync(ws + O_H0T, 0, TAGBYTES, stream);

    prep_kernel<<<3944, 256, 0, stream>>>(h0, Wih0, Whh0, bih0, bhh0,
                                          Wih1, Whh1, bih1, bhh1,
                                          Wd0, Wd1, Wout, ws);
    lstm_fused<<<2*NBLK, 512, 0, stream>>>(ws, x, c0, out);
    head_kernel<<<4096, 256, 0, stream>>>(ws, bd0, bd1, bout, out);
}

// Round 10
// 19199.919 us; speedup vs baseline: 1.4671x; 1.4671x over previous
//
#include <hip/hip_runtime.h>
#include <hip/hip_bf16.h>
#include <cstddef>
#include <cstdint>

// B=32, T=2048, D=64, H=256, O=32, 4H=1024
#define BB 32
#define TT 2048
#define DD 64
#define HH 256
#define OO 32
#define NBLK 8   // total blocks: each owns an h-slice of BOTH layers

#define OUT_ELEMS (BB*TT*OO)
#define HN_OFF OUT_ELEMS
#define CN_OFF (HN_OFF + 2*BB*HH)

// ---------------- workspace byte offsets ----------------
// h0b/h1b: [2049 slots][32 b][256 h] bf16 = 33,570,816 B each.
// h0b[s] = h0 state before L0 step s ( = y0[s-1] ).  h1b likewise for L1.
#define O_H0B   ((size_t)0)
#define O_H1B   ((size_t)33570816)
#define O_WP0   ((size_t)67141632)     // Wperm0 bf16 [1024][320]
#define O_WP1   ((size_t)67796992)     // Wperm1 bf16 [1024][512]
#define O_B0    ((size_t)68845568)     // bias0 f32 [1024]
#define O_B1    ((size_t)68849664)     // bias1 f32 [1024]
#define O_WD0T  ((size_t)68853760)     // [256][256] f32 transposed
#define O_WD1T  ((size_t)69115904)
#define O_WOUT  ((size_t)69378048)     // [256][32] f32
#define O_FLG   ((size_t)69410816)     // int[16] flags (one line), 8 used

typedef short short8 __attribute__((ext_vector_type(8)));
typedef float f32x4 __attribute__((ext_vector_type(4)));
typedef unsigned int uint4v __attribute__((ext_vector_type(4)));
typedef unsigned long long ull;

__device__ __forceinline__ float sigm_(float x){ return 1.0f/(1.0f+__expf(-x)); }
__device__ __forceinline__ float tanhf_(float x){
    float xc = fminf(fmaxf(x, -15.0f), 15.0f);
    float e = __expf(2.0f*xc);
    return (e-1.0f)/(e+1.0f);
}
__device__ __forceinline__ unsigned short f2bf(float f){
    __hip_bfloat16 h = __float2bfloat16(f);
    return *reinterpret_cast<unsigned short*>(&h);
}
__device__ __forceinline__ unsigned int pack2(float a, float b){
    return (unsigned int)f2bf(a) | ((unsigned int)f2bf(b) << 16);
}
__device__ __forceinline__ short8 ld8(const unsigned short* p){
    return *reinterpret_cast<const short8*>(p);
}
// 8 f32 -> bf16x8 (RN) for the x operand.
__device__ __forceinline__ short8 cvt8(float4 a, float4 b){
    uint4v u;
    u.x = ((unsigned)f2bf(a.y)<<16) | f2bf(a.x);
    u.y = ((unsigned)f2bf(a.w)<<16) | f2bf(a.z);
    u.z = ((unsigned)f2bf(b.y)<<16) | f2bf(b.x);
    u.w = ((unsigned)f2bf(b.w)<<16) | f2bf(b.z);
    return __builtin_bit_cast(short8, u);
}

// Every wave polls the single 8-flag line itself (lanes 0..7), sleep backoff.
// Capped: a sync bug fails validation, not the 600s limit.
__device__ __forceinline__ void pollFlags(const int* flags, int tgt, int lane){
    int it = 0;
    while (true) {
        int v = tgt;
        if (lane < NBLK)
            v = __hip_atomic_load(flags + lane, __ATOMIC_RELAXED, __HIP_MEMORY_SCOPE_AGENT);
        if (__all(v >= tgt)) break;
        __builtin_amdgcn_s_sleep(1);
        if (++it > (1<<13)) break;
    }
    asm volatile("" ::: "memory");
}

// ---------------------------------------------------------------------------
// Prep: weight-row permutation (identical math to rounds 4-5), bias sums,
// slot-0 h inits, head-weight transposes, flag zeroing.
// total = 327680+524288+1024+1024+8192+8192+65536+65536+8192+16 = 1,009,680
// ---------------------------------------------------------------------------
__global__ void prep_kernel(const float* __restrict__ h0f,
    const float* __restrict__ Wih0, const float* __restrict__ Whh0,
    const float* __restrict__ bih0, const float* __restrict__ bhh0,
    const float* __restrict__ Wih1, const float* __restrict__ Whh1,
    const float* __restrict__ bih1, const float* __restrict__ bhh1,
    const float* __restrict__ Wd0, const float* __restrict__ Wd1,
    const float* __restrict__ Wout, char* __restrict__ ws)
{
    int i = blockIdx.x*256 + threadIdx.x;
    if (i < 327680) {   // Wperm0 [1024][320]
        int R = i / 320, k = i - R*320;
        int lrow = R & 15, s = (R>>4)&1, hr = (R>>5)&3, jj = R>>7;
        int gate = 2*s + (lrow>>3);
        int h = 32*jj + 8*hr + (lrow&7);
        int src = 256*gate + h;
        float v = (k < 64) ? Wih0[src*64 + k] : Whh0[src*256 + (k-64)];
        ((unsigned short*)(ws+O_WP0))[i] = f2bf(v);
        return;
    }
    i -= 327680;
    if (i < 524288) {   // Wperm1 [1024][512]
        int R = i >> 9, k = i & 511;
        int lrow = R & 15, s = (R>>4)&1, hr = (R>>5)&3, jj = R>>7;
        int gate = 2*s + (lrow>>3);
        int h = 32*jj + 8*hr + (lrow&7);
        int src = 256*gate + h;
        float v = (k < 256) ? Wih1[src*256 + k] : Whh1[src*256 + (k-256)];
        ((unsigned short*)(ws+O_WP1))[i] = f2bf(v);
        return;
    }
    i -= 524288;
    if (i < 1024) { ((float*)(ws+O_B0))[i] = bih0[i] + bhh0[i]; return; }
    i -= 1024;
    if (i < 1024) { ((float*)(ws+O_B1))[i] = bih1[i] + bhh1[i]; return; }
    i -= 1024;
    if (i < 8192) { ((unsigned short*)(ws+O_H0B))[i] = f2bf(h0f[i]); return; }      // h0b[0]
    i -= 8192;
    if (i < 8192) { ((unsigned short*)(ws+O_H1B))[i] = f2bf(h0f[8192+i]); return; } // h1b[0]
    i -= 8192;
    if (i < 65536) { int o = i & 255, h = i >> 8; ((float*)(ws+O_WD0T))[i] = Wd0[o*256 + h]; return; }
    i -= 65536;
    if (i < 65536) { int o = i & 255, h = i >> 8; ((float*)(ws+O_WD1T))[i] = Wd1[o*256 + h]; return; }
    i -= 65536;
    if (i < 8192) { int o = i & 31, h = i >> 5; ((float*)(ws+O_WOUT))[i] = Wout[o*256 + h]; return; }
    i -= 8192;
    if (i < 16) { ((int*)(ws+O_FLG))[i] = 0; return; }
}

// ---------------------------------------------------------------------------
// Merged-layer persistent LSTM.  8 blocks x 512 threads (8 waves).
// Block j owns h-slice [32j,32j+32) of BOTH layers: waves 0-3 = L0 (hr=wv),
// waves 4-7 = L1 (hr=wv-4).  Iteration t: L0 computes step t (h0b[t]->
// h0b[t+1]); L1 computes step t-1 (h1b[t-1], y0=h0b[t] -> h1b[t]).  All
// inputs come from iteration t-1 => ONE flag per block per iteration.
// No barriers in the loop: each wave drains vmcnt, bumps an LDS counter;
// the 8th wave stores the block flag.  A-frags pinned in VGPRs.
// mfma_f32_16x16x32_bf16: A lane l -> A[row=l&15][k=(l>>4)*8+j];
//                         B lane l -> B[k][col=l&15];
//                         D lane l -> D[row=(l>>4)*4+r][col=l&15].
// ---------------------------------------------------------------------------
__global__ __launch_bounds__(512, 1) void lstm_fused(char* __restrict__ ws,
                                                     const float* __restrict__ xin,
                                                     const float* __restrict__ c0f,
                                                     float* __restrict__ out)
{
    __shared__ int ctr[TT + 2];   // per-iteration arrival counters (no resets)

    const int j    = blockIdx.x;
    const int tid  = threadIdx.x;
    const int wv   = tid >> 6;
    const int lane = tid & 63;
    const int L    = wv >> 2;
    const int hr   = wv & 3;
    const int lrow = lane & 15;
    const int q    = lane >> 4;
    const int qe   = q & 1;
    const int koff = q * 8;
    const bool lo  = lane < 32;
    const int hbase = 32*j + 8*hr + 4*qe;

    for (int i = tid; i < TT + 2; i += 512) ctr[i] = 0;
    __syncthreads();   // once, before the loop

    const unsigned short* Wp = (const unsigned short*)(ws + (L ? O_WP1 : O_WP0));
    const float* bias = (const float*)(ws + (L ? O_B1 : O_B0));
    unsigned short* h0b = (unsigned short*)(ws + O_H0B);
    unsigned short* h1b = (unsigned short*)(ws + O_H1B);
    int* flags = (int*)(ws + O_FLG);

    // ---- A fragments (prep-permuted rows), VGPR-resident; static indexing ----
    const int wavebase = (j*4 + hr) * 32;
    short8 a0[16], a1[16];
    if (L == 0) {
#pragma unroll
        for (int kk = 0; kk < 10; ++kk) {
            a0[kk] = ld8(Wp + (size_t)(wavebase +      lrow)*320 + kk*32 + koff);
            a1[kk] = ld8(Wp + (size_t)(wavebase + 16 + lrow)*320 + kk*32 + koff);
        }
    } else {
#pragma unroll
        for (int kk = 0; kk < 16; ++kk) {
            a0[kk] = ld8(Wp + (size_t)(wavebase +      lrow)*512 + kk*32 + koff);
            a1[kk] = ld8(Wp + (size_t)(wavebase + 16 + lrow)*512 + kk*32 + koff);
        }
    }

    float bI[4], bF[4], bG[4], bO[4], c[2][4], hv[2][4];
#pragma unroll
    for (int r = 0; r < 4; ++r) {
        int hg = hbase + r;
        bI[r] = bias[hg];      bF[r] = bias[256+hg];
        bG[r] = bias[512+hg];  bO[r] = bias[768+hg];
    }
#pragma unroll
    for (int ct = 0; ct < 2; ++ct)
#pragma unroll
    for (int r = 0; r < 4; ++r) {
        c[ct][r]  = c0f[(size_t)L*8192 + (ct*16+lrow)*256 + hbase + r];
        hv[ct][r] = 0.f;
    }

    for (int t = 0; t <= TT; ++t) {
        // L0: prefetch x (static input) before the poll
        float4 xf0, xf1, xf2, xf3, xf4, xf5, xf6, xf7;
        if (L == 0 && t < TT) {
            const float4* xA = (const float4*)(xin + ((size_t)lrow*TT + t)*64 + koff);
            const float4* xB = (const float4*)(xin + ((size_t)(16+lrow)*TT + t)*64 + koff);
            xf0 = xA[0]; xf1 = xA[1]; xf2 = xA[8]; xf3 = xA[9];
            xf4 = xB[0]; xf5 = xB[1]; xf6 = xB[8]; xf7 = xB[9];
        }

        pollFlags(flags, t, lane);   // all of iteration t-1 visible

        bool wrote = false;
        unsigned short* dbuf = nullptr;
        int slot = 0;
        f32x4 A00 = {0,0,0,0}, A01 = {0,0,0,0}, A10 = {0,0,0,0}, A11 = {0,0,0,0};

        if (L == 0) {
            if (t < TT) {
                const unsigned short* hp = h0b + (size_t)t*8192 + lrow*256 + koff;
                short8 bx;
                bx = cvt8(xf0, xf1);
                A00 = __builtin_amdgcn_mfma_f32_16x16x32_bf16(a0[0], bx, A00, 0,0,0);
                A01 = __builtin_amdgcn_mfma_f32_16x16x32_bf16(a1[0], bx, A01, 0,0,0);
                bx = cvt8(xf2, xf3);
                A00 = __builtin_amdgcn_mfma_f32_16x16x32_bf16(a0[1], bx, A00, 0,0,0);
                A01 = __builtin_amdgcn_mfma_f32_16x16x32_bf16(a1[1], bx, A01, 0,0,0);
                bx = cvt8(xf4, xf5);
                A10 = __builtin_amdgcn_mfma_f32_16x16x32_bf16(a0[0], bx, A10, 0,0,0);
                A11 = __builtin_amdgcn_mfma_f32_16x16x32_bf16(a1[0], bx, A11, 0,0,0);
                bx = cvt8(xf6, xf7);
                A10 = __builtin_amdgcn_mfma_f32_16x16x32_bf16(a0[1], bx, A10, 0,0,0);
                A11 = __builtin_amdgcn_mfma_f32_16x16x32_bf16(a1[1], bx, A11, 0,0,0);
#pragma unroll
                for (int kk = 0; kk < 8; ++kk) {
                    short8 b0 = ld8(hp + kk*32);
                    short8 b1 = ld8(hp + 4096 + kk*32);
                    A00 = __builtin_amdgcn_mfma_f32_16x16x32_bf16(a0[2+kk], b0, A00, 0,0,0);
                    A01 = __builtin_amdgcn_mfma_f32_16x16x32_bf16(a1[2+kk], b0, A01, 0,0,0);
                    A10 = __builtin_amdgcn_mfma_f32_16x16x32_bf16(a0[2+kk], b1, A10, 0,0,0);
                    A11 = __builtin_amdgcn_mfma_f32_16x16x32_bf16(a1[2+kk], b1, A11, 0,0,0);
                }
                wrote = true; dbuf = h0b; slot = t + 1;
            }
        } else {
            if (t >= 1) {
                const unsigned short* yp = h0b + (size_t)t*8192     + lrow*256 + koff;
                const unsigned short* hp = h1b + (size_t)(t-1)*8192 + lrow*256 + koff;
#pragma unroll
                for (int kk = 0; kk < 8; ++kk) {
                    short8 b0 = ld8(yp + kk*32);
                    short8 b1 = ld8(yp + 4096 + kk*32);
                    A00 = __builtin_amdgcn_mfma_f32_16x16x32_bf16(a0[kk], b0, A00, 0,0,0);
                    A01 = __builtin_amdgcn_mfma_f32_16x16x32_bf16(a1[kk], b0, A01, 0,0,0);
                    A10 = __builtin_amdgcn_mfma_f32_16x16x32_bf16(a0[kk], b1, A10, 0,0,0);
                    A11 = __builtin_amdgcn_mfma_f32_16x16x32_bf16(a1[kk], b1, A11, 0,0,0);
                }
#pragma unroll
                for (int kk = 0; kk < 8; ++kk) {
                    short8 b0 = ld8(hp + kk*32);
                    short8 b1 = ld8(hp + 4096 + kk*32);
                    A00 = __builtin_amdgcn_mfma_f32_16x16x32_bf16(a0[8+kk], b0, A00, 0,0,0);
                    A01 = __builtin_amdgcn_mfma_f32_16x16x32_bf16(a1[8+kk], b0, A01, 0,0,0);
                    A10 = __builtin_amdgcn_mfma_f32_16x16x32_bf16(a0[8+kk], b1, A10, 0,0,0);
                    A11 = __builtin_amdgcn_mfma_f32_16x16x32_bf16(a1[8+kk], b1, A11, 0,0,0);
                }
                wrote = true; dbuf = h1b; slot = t;
            }
        }

        if (wrote) {
            // register combine (lane<->lane+32 swap pairs (i,f),(g,o)) + store
#pragma unroll
            for (int ct = 0; ct < 2; ++ct) {
                f32x4 A0 = ct ? A10 : A00;
                f32x4 A1 = ct ? A11 : A01;
#pragma unroll
                for (int r = 0; r < 4; ++r) {
                    float x0 = A0[r], y0 = __shfl_xor(x0, 32, 64);
                    float x1 = A1[r], y1 = __shfl_xor(x1, 32, 64);
                    float gi = (lo ? x0 : y0) + bI[r];
                    float gf = (lo ? y0 : x0) + bF[r];
                    float gg = (lo ? x1 : y1) + bG[r];
                    float go = (lo ? y1 : x1) + bO[r];
                    float iv = sigm_(gi), fv = sigm_(gf), gv = tanhf_(gg), ov = sigm_(go);
                    c[ct][r]  = fv*c[ct][r] + iv*gv;
                    hv[ct][r] = ov * tanhf_(c[ct][r]);
                }
                if (lo) {
                    ull w = (ull)pack2(hv[ct][0], hv[ct][1]) |
                            ((ull)pack2(hv[ct][2], hv[ct][3]) << 32);
                    ull* dp = (ull*)(dbuf + (size_t)slot*8192 + (ct*16+lrow)*256 + hbase);
                    __hip_atomic_store(dp, w, __ATOMIC_RELAXED, __HIP_MEMORY_SCOPE_AGENT);
                }
            }
        }

        // per-wave: drain own stores, then arrive; 8th arrival publishes flag
        asm volatile("s_waitcnt vmcnt(0)" ::: "memory");
        if (lane == 0) {
            int old = atomicAdd(&ctr[t], 1);
            if (old == 7)
                __hip_atomic_store(flags + j, t + 1,
                                   __ATOMIC_RELAXED, __HIP_MEMORY_SCOPE_AGENT);
        }
    }

    // epilogue: h_n / c_n (f32, from registers)
    if (lo) {
#pragma unroll
        for (int ct = 0; ct < 2; ++ct)
#pragma unroll
        for (int r = 0; r < 4; ++r) {
            out[HN_OFF + (size_t)L*8192 + (ct*16+lrow)*256 + hbase + r] = hv[ct][r];
            out[CN_OFF + (size_t)L*8192 + (ct*16+lrow)*256 + hbase + r] = c[ct][r];
        }
    }
}

// ---------------------------------------------------------------------------
// Fused dense head: y1[t] = h1b[t+1] (bf16).
// ---------------------------------------------------------------------------
__global__ __launch_bounds__(256) void head_kernel(const char* __restrict__ ws,
    const float* __restrict__ bd0, const float* __restrict__ bd1,
    const float* __restrict__ bout, float* __restrict__ out)
{
    const __hip_bfloat16* h1b = (const __hip_bfloat16*)(ws + O_H1B);
    const float* Wd0T  = (const float*)(ws + O_WD0T);
    const float* Wd1T  = (const float*)(ws + O_WD1T);
    const float* WoutT = (const float*)(ws + O_WOUT);

    __shared__ float buf0[16][256];
    __shared__ float buf1[16][256];
    const int row0 = blockIdx.x * 16;
    const int tid = threadIdx.x;

#pragma unroll
    for (int i = 0; i < 16; ++i) {
        int r = row0 + i;
        int b = r >> 11, t = r & 2047;
        buf0[i][tid] = __bfloat162float(h1b[(size_t)(t+1)*8192 + b*256 + tid]);
    }
    __syncthreads();

    {   // stage 1: Linear+ReLU
        float acc[16];
        float bv = bd0[tid];
#pragma unroll
        for (int r = 0; r < 16; ++r) acc[r] = bv;
        for (int h = 0; h < 256; ++h) {
            float w = Wd0T[h*256 + tid];
#pragma unroll
            for (int r = 0; r < 16; ++r) acc[r] += w * buf0[r][h];
        }
        __syncthreads();
#pragma unroll
        for (int r = 0; r < 16; ++r) buf1[r][tid] = fmaxf(acc[r], 0.0f);
    }
    __syncthreads();

    {   // stage 2: Linear+ReLU
        float acc[16];
        float bv = bd1[tid];
#pragma unroll
        for (int r = 0; r < 16; ++r) acc[r] = bv;
        for (int h = 0; h < 256; ++h) {
            float w = Wd1T[h*256 + tid];
#pragma unroll
            for (int r = 0; r < 16; ++r) acc[r] += w * buf1[r][h];
        }
        __syncthreads();
#pragma unroll
        for (int r = 0; r < 16; ++r) buf0[r][tid] = fmaxf(acc[r], 0.0f);
    }
    __syncthreads();

    {   // stage 3: output Linear
        const int o = tid & 31;
        const int rr = tid >> 5;
        float a0 = bout[o], a1 = bout[o];
        for (int h = 0; h < 256; ++h) {
            float w = WoutT[h*32 + o];
            a0 += w * buf0[rr*2 + 0][h];
            a1 += w * buf0[rr*2 + 1][h];
        }
        out[(size_t)(row0 + rr*2 + 0)*32 + o] = a0;
        out[(size_t)(row0 + rr*2 + 1)*32 + o] = a1;
    }
}

// ---------------------------------------------------------------------------
extern "C" void kernel_launch(void* const* d_in, const int* in_sizes, int n_in,
                              void* d_out, int out_size, void* d_ws, size_t ws_size,
                              hipStream_t stream) {
    const float* x    = (const float*)d_in[0];
    const float* h0   = (const float*)d_in[1];
    const float* c0   = (const float*)d_in[2];
    const float* Wih0 = (const float*)d_in[3];
    const float* Whh0 = (const float*)d_in[4];
    const float* bih0 = (const float*)d_in[5];
    const float* bhh0 = (const float*)d_in[6];
    const float* Wih1 = (const float*)d_in[7];
    const float* Whh1 = (const float*)d_in[8];
    const float* bih1 = (const float*)d_in[9];
    const float* bhh1 = (const float*)d_in[10];
    const float* Wd0  = (const float*)d_in[11];
    const float* bd0  = (const float*)d_in[12];
    const float* Wd1  = (const float*)d_in[13];
    const float* bd1  = (const float*)d_in[14];
    const float* Wout = (const float*)d_in[15];
    const float* bout = (const float*)d_in[16];

    char* ws = (char*)d_ws;
    float* out = (float*)d_out;

    prep_kernel<<<3945, 256, 0, stream>>>(h0, Wih0, Whh0, bih0, bhh0,
                                          Wih1, Whh1, bih1, bhh1,
                                          Wd0, Wd1, Wout, ws);
    lstm_fused<<<NBLK, 512, 0, stream>>>(ws, x, c0, out);
    head_kernel<<<4096, 256, 0, stream>>>(ws, bd0, bd1, bout, out);
}

// Round 11
// 12192.964 us; speedup vs baseline: 2.3102x; 1.5747x over previous
//
#include <hip/hip_runtime.h>
#include <hip/hip_bf16.h>
#include <cstddef>
#include <cstdint>

// B=32, T=2048, D=64, H=256, O=32, 4H=1024
#define BB 32
#define TT 2048
#define DD 64
#define HH 256
#define OO 32
#define NBLK 8   // blocks per layer

#define OUT_ELEMS (BB*TT*OO)
#define HN_OFF OUT_ELEMS
#define CN_OFF (HN_OFF + 2*BB*HH)

// ---------------- workspace byte offsets (round-5 map, unchanged) ----------------
#define O_XBF   ((size_t)0)                     // x bf16 [T][B][64]
#define O_H0    ((size_t)8388608)               // h0buf bf16 [2049][32][256]
#define O_XH1   ((size_t)41959424)              // xh1 bf16 [2049][32][512]
#define O_WP0   ((size_t)109101056)             // Wperm0 bf16 [1024][320]
#define O_WP1   ((size_t)109756416)             // Wperm1 bf16 [1024][512]
#define O_B0    ((size_t)110804992)             // bias0 f32 [1024]
#define O_B1    ((size_t)110809088)             // bias1 f32 [1024]
#define O_WD0T  ((size_t)110813184)             // [256][256] f32 transposed
#define O_WD1T  ((size_t)111075328)
#define O_WOUT  ((size_t)111337472)             // [256][32] f32
#define O_D0    ((size_t)111370240)             // flags layer0: int[8]
#define O_D1    (O_D0 + 256)                    // flags layer1: int[8]

typedef short short8 __attribute__((ext_vector_type(8)));
typedef float f32x4 __attribute__((ext_vector_type(4)));

// Register pin: read-write no-op asm makes the fragment loop-carried state ->
// the allocator cannot rematerialize (re-load) it inside the loop; it must
// stay live in VGPRs for the whole t-loop.  Emits ZERO instructions.
#define PIN8(x) asm volatile("" : "+v"(x))

__device__ __forceinline__ float sigm_(float x){ return 1.0f/(1.0f+__expf(-x)); }
__device__ __forceinline__ float tanhf_(float x){
    float xc = fminf(fmaxf(x, -15.0f), 15.0f);
    float e = __expf(2.0f*xc);
    return (e-1.0f)/(e+1.0f);
}
__device__ __forceinline__ unsigned short f2bf(float f){
    __hip_bfloat16 h = __float2bfloat16(f);
    return *reinterpret_cast<unsigned short*>(&h);
}
__device__ __forceinline__ unsigned int pack2(float a, float b){
    return (unsigned int)f2bf(a) | ((unsigned int)f2bf(b) << 16);
}
__device__ __forceinline__ short8 ld8(const unsigned short* p){
    return *reinterpret_cast<const short8*>(p);
}

// Single-poller primitives (proven rounds 4-5): wave 0 only; one LLC line per
// round; s_sleep backoff; capped so bugs fail validation instead of hanging.
__device__ __forceinline__ void pollLine(const int* flags, int tgt, int lane){
    int it = 0;
    while (true) {
        int v = tgt;
        if (lane < NBLK)
            v = __hip_atomic_load(flags + lane, __ATOMIC_RELAXED, __HIP_MEMORY_SCOPE_AGENT);
        if (__all(v >= tgt)) break;
        __builtin_amdgcn_s_sleep(1);
        if (++it > (1<<16)) break;
    }
    asm volatile("" ::: "memory");
}

__device__ __forceinline__ void pollTwo(const int* f0, int t0,
                                        const int* f1, int t1, int lane){
    const int* p = (lane < 8) ? (f0 + lane) : (f1 + (lane - 8));
    const int tgt = (lane < 8) ? t0 : t1;
    int it = 0;
    while (true) {
        int v = tgt;
        if (lane < 16)
            v = __hip_atomic_load(p, __ATOMIC_RELAXED, __HIP_MEMORY_SCOPE_AGENT);
        if (__all(v >= tgt)) break;
        __builtin_amdgcn_s_sleep(1);
        if (++it > (1<<16)) break;
    }
    asm volatile("" ::: "memory");
}

// ---------------------------------------------------------------------------
// Prep (identical to rounds 4-5).
// ---------------------------------------------------------------------------
__global__ void prep_kernel(const float* __restrict__ x, const float* __restrict__ h0,
    const float* __restrict__ Wih0, const float* __restrict__ Whh0,
    const float* __restrict__ bih0, const float* __restrict__ bhh0,
    const float* __restrict__ Wih1, const float* __restrict__ Whh1,
    const float* __restrict__ bih1, const float* __restrict__ bhh1,
    const float* __restrict__ Wd0, const float* __restrict__ Wd1,
    const float* __restrict__ Wout, char* __restrict__ ws)
{
    int i = blockIdx.x*256 + threadIdx.x;
    if (i < 4194304) {  // x [B][T][D] -> xbf2 [T][B][D] bf16
        int t = i >> 11, rem = i & 2047, b = rem >> 6, d = rem & 63;
        ((unsigned short*)(ws+O_XBF))[i] = f2bf(x[(size_t)b*131072 + t*64 + d]);
        return;
    }
    i -= 4194304;
    if (i < 327680) {   // Wperm0 [1024][320]
        int R = i / 320, k = i - R*320;
        int lrow = R & 15, s = (R>>4)&1, hr = (R>>5)&3, jj = R>>7;
        int gate = 2*s + (lrow>>3);
        int h = 32*jj + 8*hr + (lrow&7);
        int src = 256*gate + h;
        float v = (k < 64) ? Wih0[src*64 + k] : Whh0[src*256 + (k-64)];
        ((unsigned short*)(ws+O_WP0))[i] = f2bf(v);
        return;
    }
    i -= 327680;
    if (i < 524288) {   // Wperm1 [1024][512]
        int R = i >> 9, k = i & 511;
        int lrow = R & 15, s = (R>>4)&1, hr = (R>>5)&3, jj = R>>7;
        int gate = 2*s + (lrow>>3);
        int h = 32*jj + 8*hr + (lrow&7);
        int src = 256*gate + h;
        float v = (k < 256) ? Wih1[src*256 + k] : Whh1[src*256 + (k-256)];
        ((unsigned short*)(ws+O_WP1))[i] = f2bf(v);
        return;
    }
    i -= 524288;
    if (i < 1024) { ((float*)(ws+O_B0))[i] = bih0[i] + bhh0[i]; return; }
    i -= 1024;
    if (i < 1024) { ((float*)(ws+O_B1))[i] = bih1[i] + bhh1[i]; return; }
    i -= 1024;
    if (i < 8192) { ((unsigned short*)(ws+O_H0))[i] = f2bf(h0[i]); return; }   // h0buf[0]
    i -= 8192;
    if (i < 8192) {     // xh1[0][b][256+h] = h0[1][b][h]
        int b = i >> 8, h = i & 255;
        ((unsigned short*)(ws+O_XH1))[b*512 + 256 + h] = f2bf(h0[8192 + i]);
        return;
    }
    i -= 8192;
    if (i < 65536) { int o = i & 255, h = i >> 8; ((float*)(ws+O_WD0T))[i] = Wd0[o*256 + h]; return; }
    i -= 65536;
    if (i < 65536) { int o = i & 255, h = i >> 8; ((float*)(ws+O_WD1T))[i] = Wd1[o*256 + h]; return; }
    i -= 65536;
    if (i < 8192) { int o = i & 31, h = i >> 5; ((float*)(ws+O_WOUT))[i] = Wout[o*256 + h]; return; }
    i -= 8192;
    if (i < 4096) { ((int*)(ws+O_D0))[i] = 0; return; }   // flag region
}

// ---------------------------------------------------------------------------
// Persistent LSTM (round-5 structure, weights GENUINELY pinned in VGPRs).
// 8 blocks/layer x 512 threads (8 waves).  Wave (hr,bh) of block j owns all
// 4 gates for h-range [32j+8hr,+8) x batches [16bh,+16).  Per step:
// [pre-poll MFMAs on static inputs] -> wave0 polls flag line(s) ->
// __syncthreads broadcast -> B-frag loads -> MFMAs -> shfl_xor register
// gate-combine -> sc1 stores -> __syncthreads (drains vmcnt) -> tid0 flag.
// TRIPWIRE: kernel VGPR_Count must read ~210-240; <=130 means the pin failed
// and weights are still being re-streamed from L2 every step.
// ---------------------------------------------------------------------------
template<int L>
__device__ void lstm_body(int j, char* ws, const float* __restrict__ c0_in,
                          float* __restrict__ out)
{
    constexpr int KK  = L ? 512 : 320;
    constexpr int NKT = KK / 32;

    const int tid  = threadIdx.x;
    const int wv   = tid >> 6;
    const int lane = tid & 63;
    const int bh   = wv >> 2;
    const int hr   = wv & 3;
    const int lrow = lane & 15;
    const int q    = lane >> 4;
    const int koff = q * 8;
    const int qe   = q & 1;
    const int fb   = bh*16 + lrow;
    const int hbase= 32*j + 8*hr + 4*qe;
    const bool lo  = (lane < 32);

    const unsigned short* Wp = (const unsigned short*)(ws + (L ? O_WP1 : O_WP0));
    const float* bias = (const float*)(ws + (L ? O_B1 : O_B0));

    const int wavebase = (j*4 + hr) * 32;
    short8 a0[NKT], a1[NKT];
#pragma unroll
    for (int kk = 0; kk < NKT; ++kk) {
        a0[kk] = ld8(Wp + (size_t)(wavebase +      lrow)*KK + kk*32 + koff);
        a1[kk] = ld8(Wp + (size_t)(wavebase + 16 + lrow)*KK + kk*32 + koff);
    }

    float bi[4], bf_[4], bg[4], bo[4], c[4], hv[4];
#pragma unroll
    for (int r = 0; r < 4; ++r) {
        int hg = hbase + r;
        bi[r] = bias[hg];       bf_[r] = bias[256+hg];
        bg[r] = bias[512+hg];   bo[r]  = bias[768+hg];
        c[r]  = c0_in[(size_t)L*8192 + fb*256 + hg];
        hv[r] = 0.f;
    }

    int* flags0 = (int*)(ws + O_D0);
    int* flags1 = (int*)(ws + O_D1);
    int* myflag = (L ? flags1 : flags0) + j;

    const unsigned short* xb = (const unsigned short*)(ws + O_XBF) + fb*64  + koff;
    const unsigned short* hb = (const unsigned short*)(ws + O_H0)  + fb*256 + koff;
    const unsigned short* xh = (const unsigned short*)(ws + O_XH1) + fb*512 + koff;

    unsigned long long* stA;
    unsigned long long* stB = nullptr;
    if (L == 0) {
        stA = (unsigned long long*)((unsigned short*)(ws + O_H0)  + (size_t)8192 + fb*256 + hbase);
        stB = (unsigned long long*)((unsigned short*)(ws + O_XH1) + (size_t)fb*512 + hbase);
    } else {
        stA = (unsigned long long*)((unsigned short*)(ws + O_XH1) + (size_t)16384 + fb*512 + 256 + hbase);
    }

    for (int t = 0; t < TT; ++t) {
        // --- pin the weight fragments: loop-carried, un-rematerializable ---
#pragma unroll
        for (int kk = 0; kk < NKT; ++kk) { PIN8(a0[kk]); PIN8(a1[kk]); }

        f32x4 A0 = {0.f,0.f,0.f,0.f}, A1 = {0.f,0.f,0.f,0.f};

        if (L == 0) {
            short8 bx0 = ld8(xb), bx1 = ld8(xb + 32);
            A0 = __builtin_amdgcn_mfma_f32_16x16x32_bf16(a0[0], bx0, A0, 0,0,0);
            A1 = __builtin_amdgcn_mfma_f32_16x16x32_bf16(a1[0], bx0, A1, 0,0,0);
            A0 = __builtin_amdgcn_mfma_f32_16x16x32_bf16(a0[1], bx1, A0, 0,0,0);
            A1 = __builtin_amdgcn_mfma_f32_16x16x32_bf16(a1[1], bx1, A1, 0,0,0);

            if (wv == 0) pollLine(flags0, t, lane);
            __syncthreads();

            short8 b[8];
#pragma unroll
            for (int kk = 0; kk < 8; ++kk) b[kk] = ld8(hb + 32*kk);
#pragma unroll
            for (int kk = 0; kk < 8; ++kk) {
                A0 = __builtin_amdgcn_mfma_f32_16x16x32_bf16(a0[2+kk], b[kk], A0, 0,0,0);
                A1 = __builtin_amdgcn_mfma_f32_16x16x32_bf16(a1[2+kk], b[kk], A1, 0,0,0);
            }
        } else {
            if (wv == 0) pollTwo(flags0, t+1, flags1, t, lane);
            __syncthreads();

            short8 b[8];
#pragma unroll
            for (int kk = 0; kk < 8; ++kk) b[kk] = ld8(xh + 32*kk);
#pragma unroll
            for (int kk = 0; kk < 8; ++kk) {
                A0 = __builtin_amdgcn_mfma_f32_16x16x32_bf16(a0[kk], b[kk], A0, 0,0,0);
                A1 = __builtin_amdgcn_mfma_f32_16x16x32_bf16(a1[kk], b[kk], A1, 0,0,0);
            }
#pragma unroll
            for (int kk = 0; kk < 8; ++kk) b[kk] = ld8(xh + 256 + 32*kk);
#pragma unroll
            for (int kk = 0; kk < 8; ++kk) {
                A0 = __builtin_amdgcn_mfma_f32_16x16x32_bf16(a0[8+kk], b[kk], A0, 0,0,0);
                A1 = __builtin_amdgcn_mfma_f32_16x16x32_bf16(a1[8+kk], b[kk], A1, 0,0,0);
            }
        }

#pragma unroll
        for (int r = 0; r < 4; ++r) {
            float x0 = A0[r], y0 = __shfl_xor(x0, 32, 64);
            float x1 = A1[r], y1 = __shfl_xor(x1, 32, 64);
            float gi = (lo ? x0 : y0) + bi[r];
            float gf = (lo ? y0 : x0) + bf_[r];
            float gg = (lo ? x1 : y1) + bg[r];
            float go = (lo ? y1 : x1) + bo[r];
            float iv = sigm_(gi), fv = sigm_(gf), gv = tanhf_(gg), ov = sigm_(go);
            c[r]  = fv*c[r] + iv*gv;
            hv[r] = ov * tanhf_(c[r]);
        }

        unsigned long long w =
            (unsigned long long)pack2(hv[0], hv[1]) |
            ((unsigned long long)pack2(hv[2], hv[3]) << 32);

        if (L == 0) {
            if (lo) __hip_atomic_store(stA, w, __ATOMIC_RELAXED, __HIP_MEMORY_SCOPE_AGENT);
            else    __hip_atomic_store(stB, w, __ATOMIC_RELAXED, __HIP_MEMORY_SCOPE_AGENT);
        } else {
            if (lo) __hip_atomic_store(stA, w, __ATOMIC_RELAXED, __HIP_MEMORY_SCOPE_AGENT);
        }

        // barrier drains every wave's vmcnt (stores LLC-visible) before flag
        __syncthreads();
        if (tid == 0)
            __hip_atomic_store(myflag, t+1, __ATOMIC_RELAXED, __HIP_MEMORY_SCOPE_AGENT);

        xb += 2048; hb += 8192; xh += 16384;
        stA += (L ? 4096 : 2048);
        if (L == 0) stB += 4096;
    }

    if (lo) {
#pragma unroll
        for (int r = 0; r < 4; ++r) {
            out[HN_OFF + (size_t)L*8192 + fb*256 + hbase + r] = hv[r];
            out[CN_OFF + (size_t)L*8192 + fb*256 + hbase + r] = c[r];
        }
    }
}

__global__ __launch_bounds__(512, 1) void lstm_fused(char* ws,
                                                     const float* __restrict__ c0_in,
                                                     float* __restrict__ out)
{
    if (blockIdx.x < NBLK) lstm_body<0>(blockIdx.x, ws, c0_in, out);
    else                   lstm_body<1>(blockIdx.x - NBLK, ws, c0_in, out);
}

// ---------------------------------------------------------------------------
// Fused dense head (identical to round 5).
// ---------------------------------------------------------------------------
__global__ __launch_bounds__(256) void head_kernel(const char* __restrict__ ws,
    const float* __restrict__ bd0, const float* __restrict__ bd1,
    const float* __restrict__ bout, float* __restrict__ out)
{
    const __hip_bfloat16* xh1 = (const __hip_bfloat16*)(ws + O_XH1);
    const float* Wd0T  = (const float*)(ws + O_WD0T);
    const float* Wd1T  = (const float*)(ws + O_WD1T);
    const float* WoutT = (const float*)(ws + O_WOUT);

    __shared__ float buf0[16][256];
    __shared__ float buf1[16][256];
    const int row0 = blockIdx.x * 16;
    const int tid = threadIdx.x;

#pragma unroll
    for (int i = 0; i < 16; ++i) {
        int r = row0 + i;
        int b = r >> 11, t = r & 2047;
        buf0[i][tid] = __bfloat162float(xh1[(size_t)(t+1)*16384 + b*512 + 256 + tid]);
    }
    __syncthreads();

    {   // stage 1: Linear+ReLU
        float acc[16];
        float bv = bd0[tid];
#pragma unroll
        for (int r = 0; r < 16; ++r) acc[r] = bv;
        for (int h = 0; h < 256; ++h) {
            float w = Wd0T[h*256 + tid];
#pragma unroll
            for (int r = 0; r < 16; ++r) acc[r] += w * buf0[r][h];
        }
        __syncthreads();
#pragma unroll
        for (int r = 0; r < 16; ++r) buf1[r][tid] = fmaxf(acc[r], 0.0f);
    }
    __syncthreads();

    {   // stage 2: Linear+ReLU
        float acc[16];
        float bv = bd1[tid];
#pragma unroll
        for (int r = 0; r < 16; ++r) acc[r] = bv;
        for (int h = 0; h < 256; ++h) {
            float w = Wd1T[h*256 + tid];
#pragma unroll
            for (int r = 0; r < 16; ++r) acc[r] += w * buf1[r][h];
        }
        __syncthreads();
#pragma unroll
        for (int r = 0; r < 16; ++r) buf0[r][tid] = fmaxf(acc[r], 0.0f);
    }
    __syncthreads();

    {   // stage 3: output Linear
        const int o = tid & 31;
        const int rr = tid >> 5;
        float a0 = bout[o], a1 = bout[o];
        for (int h = 0; h < 256; ++h) {
            float w = WoutT[h*32 + o];
            a0 += w * buf0[rr*2 + 0][h];
            a1 += w * buf0[rr*2 + 1][h];
        }
        out[(size_t)(row0 + rr*2 + 0)*32 + o] = a0;
        out[(size_t)(row0 + rr*2 + 1)*32 + o] = a1;
    }
}

// ---------------------------------------------------------------------------
extern "C" void kernel_launch(void* const* d_in, const int* in_sizes, int n_in,
                              void* d_out, int out_size, void* d_ws, size_t ws_size,
                              hipStream_t stream) {
    const float* x    = (const float*)d_in[0];
    const float* h0   = (const float*)d_in[1];
    const float* c0   = (const float*)d_in[2];
    const float* Wih0 = (const float*)d_in[3];
    const float* Whh0 = (const float*)d_in[4];
    const float* bih0 = (const float*)d_in[5];
    const float* bhh0 = (const float*)d_in[6];
    const float* Wih1 = (const float*)d_in[7];
    const float* Whh1 = (const float*)d_in[8];
    const float* bih1 = (const float*)d_in[9];
    const float* bhh1 = (const float*)d_in[10];
    const float* Wd0  = (const float*)d_in[11];
    const float* bd0  = (const float*)d_in[12];
    const float* Wd1  = (const float*)d_in[13];
    const float* bd1  = (const float*)d_in[14];
    const float* Wout = (const float*)d_in[15];
    const float* bout = (const float*)d_in[16];

    char* ws = (char*)d_ws;
    float* out = (float*)d_out;

    prep_kernel<<<20344, 256, 0, stream>>>(x, h0, Wih0, Whh0, bih0, bhh0,
                                           Wih1, Whh1, bih1, bhh1,
                                           Wd0, Wd1, Wout, ws);
    lstm_fused<<<2*NBLK, 512, 0, stream>>>(ws, c0, out);
    head_kernel<<<4096, 256, 0, stream>>>(ws, bd0, bd1, bout, out);
}